// Round 2
// baseline (257.280 us; speedup 1.0000x reference)
//
#include <hip/hip_runtime.h>
#include <math.h>

// out[b,c,n] = softmax_n(max_c x[b,c,n]) * x[b,c,n]   (x: [256,64,2048] fp32)
//
// R4b: resubmit of R4 (infra failure, no counters). Split the monolithic
// 1-block-per-CU barrier-phased kernel into three stream-pure kernels.
// Softmax only needs the 8KB xm row, not the 512KB x row, so the heavy
// phases (col-max read, gated-multiply copy) run at full grid with zero
// barriers. xm + gate staged in d_ws (4 MiB preferred); fall back to
// xm-in-out (2 MiB ws), then to the old monolithic kernel.

#define B_DIM 256
#define C_DIM 64
#define N_DIM 2048
#define COLS4 (N_DIM / 4)          // 512 float4 columns per row
#define ROW4  (C_DIM * COLS4)      // 32768 float4 per batch row (2^15)

// ---------------- K1: xm[b,n] = max_c x[b,c,n] ----------------
// grid 512 = 256 rows x 2 col-halves, 256 threads, 1 float4 column each.
// No barriers, no LDS: each column's max is thread-private.
__global__ __launch_bounds__(256)
void max_kernel(const float* __restrict__ x, float4* __restrict__ xm) {
    const int row = blockIdx.x >> 1;
    const int col = ((blockIdx.x & 1) << 8) + threadIdx.x;   // 0..511
    const float4* __restrict__ xb = (const float4*)x + (size_t)row * ROW4 + col;
    float4 m = make_float4(-INFINITY, -INFINITY, -INFINITY, -INFINITY);
    #pragma unroll 8
    for (int c = 0; c < C_DIM; ++c) {
        float4 v = xb[(size_t)c * COLS4];
        m.x = fmaxf(m.x, v.x); m.y = fmaxf(m.y, v.y);
        m.z = fmaxf(m.z, v.z); m.w = fmaxf(m.w, v.w);
    }
    xm[(size_t)row * COLS4 + col] = m;
}

// ---------------- K2: gate[b,:] = softmax(xm[b,:]) ----------------
// 256 blocks x 256 threads (4 waves), each thread 2 float4 columns.
// Traffic: 2 MiB read + 2 MiB write — a few microseconds.
__global__ __launch_bounds__(256)
void softmax_kernel(const float4* __restrict__ xm, float4* __restrict__ gate) {
    const int b    = blockIdx.x;
    const int t    = threadIdx.x;
    const int lane = t & 63;
    const int wid  = t >> 6;            // 0..3
    __shared__ float sred[8];

    const float4* __restrict__ rowp = xm + (size_t)b * COLS4;
    float4 a0 = rowp[t];
    float4 a1 = rowp[t + 256];

    float tm = fmaxf(fmaxf(fmaxf(a0.x, a0.y), fmaxf(a0.z, a0.w)),
                     fmaxf(fmaxf(a1.x, a1.y), fmaxf(a1.z, a1.w)));
    #pragma unroll
    for (int off = 32; off > 0; off >>= 1)
        tm = fmaxf(tm, __shfl_down(tm, off, 64));
    if (lane == 0) sred[wid] = tm;
    __syncthreads();
    const float M = fmaxf(fmaxf(sred[0], sred[1]), fmaxf(sred[2], sred[3]));

    float4 e0, e1;
    e0.x = __expf(a0.x - M); e0.y = __expf(a0.y - M);
    e0.z = __expf(a0.z - M); e0.w = __expf(a0.w - M);
    e1.x = __expf(a1.x - M); e1.y = __expf(a1.y - M);
    e1.z = __expf(a1.z - M); e1.w = __expf(a1.w - M);
    float ts = ((e0.x + e0.y) + (e0.z + e0.w)) + ((e1.x + e1.y) + (e1.z + e1.w));
    #pragma unroll
    for (int off = 32; off > 0; off >>= 1)
        ts += __shfl_down(ts, off, 64);
    if (lane == 0) sred[4 + wid] = ts;
    __syncthreads();
    const float inv = 1.0f / ((sred[4] + sred[5]) + (sred[6] + sred[7]));

    float4 g0, g1;
    g0.x = e0.x * inv; g0.y = e0.y * inv; g0.z = e0.z * inv; g0.w = e0.w * inv;
    g1.x = e1.x * inv; g1.y = e1.y * inv; g1.z = e1.z * inv; g1.w = e1.w * inv;
    gate[(size_t)b * COLS4 + t]       = g0;
    gate[(size_t)b * COLS4 + t + 256] = g1;
}

// ---------------- K3: out = gate * x ----------------
// Pure streaming copy-with-scale. 2048 blocks x 256 threads, 16 grid-stride
// iterations (stride 2^19 float4 => col/channel bits constant per thread).
#define MUL_BLOCKS  2048
#define MUL_THREADS 256
#define TOTAL4      (B_DIM * ROW4)                              // 8388608 = 2^23
#define MUL_STRIDE  ((size_t)MUL_BLOCKS * MUL_THREADS)          // 2^19
#define MUL_ITERS   (TOTAL4 / (MUL_BLOCKS * MUL_THREADS))       // 16

__global__ __launch_bounds__(MUL_THREADS)
void mul_kernel(const float* __restrict__ x, const float4* __restrict__ gate,
                float4* __restrict__ out4) {
    size_t i = (size_t)blockIdx.x * MUL_THREADS + threadIdx.x;
    const float4* __restrict__ x4 = (const float4*)x;
    #pragma unroll 4
    for (int it = 0; it < MUL_ITERS; ++it, i += MUL_STRIDE) {
        const int b   = (int)(i >> 15);            // / (C_DIM*COLS4)
        const int col = (int)(i & (COLS4 - 1));
        float4 g = gate[((size_t)b << 9) + col];   // 2 MiB, L2/L3-resident
        float4 v = x4[i];
        float4 o;
        o.x = v.x * g.x; o.y = v.y * g.y; o.z = v.z * g.z; o.w = v.w * g.w;
        out4[i] = o;
    }
}

// ---------------- Fallback: previous monolithic kernel (ws too small) -------
#define THREADS 1024
__global__ __launch_bounds__(THREADS)
void ssa_gate_kernel(const float* __restrict__ x, float* __restrict__ out) {
    const int b    = blockIdx.x;
    const int t    = threadIdx.x;
    const int col  = t & (COLS4 - 1);
    const int grp  = t >> 9;
    const int lane = t & 63;
    const int wid  = t >> 6;

    const size_t base = (size_t)b * (C_DIM * N_DIM);
    const float4* __restrict__ xb = (const float4*)(x + base);
    float4* ob = (float4*)(out + base);

    __shared__ float4 pm[2][COLS4];
    __shared__ float  sred[16];

    const int c0 = grp * 32;
    float4 m;
    m.x = -INFINITY; m.y = -INFINITY; m.z = -INFINITY; m.w = -INFINITY;
    #pragma unroll 8
    for (int c = 0; c < 32; ++c) {
        const int cc = c0 + ((c + b) & 31);
        float4 v = xb[(size_t)cc * COLS4 + col];
        m.x = fmaxf(m.x, v.x); m.y = fmaxf(m.y, v.y);
        m.z = fmaxf(m.z, v.z); m.w = fmaxf(m.w, v.w);
    }
    pm[grp][col] = m;
    __syncthreads();

    float4 e;
    if (t < COLS4) {
        float4 a = pm[0][t];
        float4 c2 = pm[1][t];
        e.x = fmaxf(a.x, c2.x); e.y = fmaxf(a.y, c2.y);
        e.z = fmaxf(a.z, c2.z); e.w = fmaxf(a.w, c2.w);
        float tm = fmaxf(fmaxf(e.x, e.y), fmaxf(e.z, e.w));
        #pragma unroll
        for (int off = 32; off > 0; off >>= 1)
            tm = fmaxf(tm, __shfl_down(tm, off, 64));
        if (lane == 0) sred[wid] = tm;
    }
    __syncthreads();
    float M = sred[0];
    #pragma unroll
    for (int i = 1; i < 8; ++i) M = fmaxf(M, sred[i]);

    if (t < COLS4) {
        e.x = __expf(e.x - M); e.y = __expf(e.y - M);
        e.z = __expf(e.z - M); e.w = __expf(e.w - M);
        float ts = (e.x + e.y) + (e.z + e.w);
        #pragma unroll
        for (int off = 32; off > 0; off >>= 1)
            ts += __shfl_down(ts, off, 64);
        if (lane == 0) sred[8 + wid] = ts;
    }
    __syncthreads();
    float S = 0.0f;
    #pragma unroll
    for (int i = 8; i < 16; ++i) S += sred[i];

    if (t < COLS4) {
        const float inv = 1.0f / S;
        float4 gg;
        gg.x = e.x * inv; gg.y = e.y * inv; gg.z = e.z * inv; gg.w = e.w * inv;
        pm[0][t] = gg;
    }
    __syncthreads();

    const float4 g = pm[0][col];
    #pragma unroll 8
    for (int c = 0; c < 32; ++c) {
        const int cc = c0 + ((c + b) & 31);
        const size_t idx = (size_t)cc * COLS4 + col;
        float4 v = xb[idx];
        float4 o;
        o.x = v.x * g.x; o.y = v.y * g.y; o.z = v.z * g.z; o.w = v.w * g.w;
        ob[idx] = o;
    }
}

extern "C" void kernel_launch(void* const* d_in, const int* in_sizes, int n_in,
                              void* d_out, int out_size, void* d_ws, size_t ws_size,
                              hipStream_t stream) {
    const float* x = (const float*)d_in[0];
    float* out = (float*)d_out;
    const size_t buf_bytes = (size_t)B_DIM * COLS4 * sizeof(float4);  // 2 MiB each
    if (ws_size >= 2 * buf_bytes) {
        float4* xm   = (float4*)d_ws;
        float4* gate = (float4*)((char*)d_ws + buf_bytes);
        max_kernel<<<B_DIM * 2, 256, 0, stream>>>(x, xm);
        softmax_kernel<<<B_DIM, 256, 0, stream>>>(xm, gate);
        mul_kernel<<<MUL_BLOCKS, MUL_THREADS, 0, stream>>>(x, gate, (float4*)out);
    } else if (ws_size >= buf_bytes) {
        float4* gate = (float4*)d_ws;
        float4* xm   = (float4*)out;   // scratch in out; fully overwritten by K3
        max_kernel<<<B_DIM * 2, 256, 0, stream>>>(x, xm);
        softmax_kernel<<<B_DIM, 256, 0, stream>>>(xm, gate);
        mul_kernel<<<MUL_BLOCKS, MUL_THREADS, 0, stream>>>(x, gate, (float4*)out);
    } else {
        ssa_gate_kernel<<<B_DIM, THREADS, 0, stream>>>(x, out);
    }
}

// Round 3
// 250.237 us; speedup vs baseline: 1.0281x; 1.0281x over previous
//
#include <hip/hip_runtime.h>
#include <math.h>

// out[b,c,n] = softmax_n(max_c x[b,c,n]) * x[b,c,n]   (x: [256,64,2048] fp32)
//
// R5: R4b's 3-kernel split worked at GPU level (all kernels < 79us, below the
// 80us ws-poison fills in top-5) but using d_ws added a 512MiB re-poison fill
// to the timed loop. This version: 2 kernels, NO workspace. Gate rows are
// staged in `out` itself (4 copies per row at channels 0/16/32/48); the gated
// multiply assigns each gate copy to exactly the block that overwrites it, so
// there is no cross-block race.

#define B_DIM 256
#define C_DIM 64
#define N_DIM 2048
#define COLS4 (N_DIM / 4)          // 512 float4 columns per row
#define ROW4  (C_DIM * COLS4)      // 32768 float4 per batch row

// ---------------- K_A: gate[b,:] = softmax_n(max_c x[b,c,:]) ----------------
// One block per batch row. 1024 threads: group 0 (t<512) maxes channels 0..31,
// group 1 channels 32..63; combine in LDS; softmax reduce; write 4 copies of
// the gate row into out[b, {0,16,32,48}, :].
__global__ __launch_bounds__(1024)
void gate_kernel(const float* __restrict__ x, float* __restrict__ out) {
    const int b    = blockIdx.x;
    const int t    = threadIdx.x;
    const int col  = t & (COLS4 - 1);   // 0..511
    const int grp  = t >> 9;            // 0 or 1
    const int lane = t & 63;
    const int wid  = t >> 6;            // 0..15

    const float4* __restrict__ xb = (const float4*)x + (size_t)b * ROW4;
    float4* ob = (float4*)out + (size_t)b * ROW4;

    __shared__ float4 pm[2][COLS4];     // 16 KB
    __shared__ float  sred[16];

    const int c0 = grp * 32;
    float4 m = make_float4(-INFINITY, -INFINITY, -INFINITY, -INFINITY);
    #pragma unroll 8
    for (int c = 0; c < 32; ++c) {
        float4 v = xb[(size_t)(c0 + c) * COLS4 + col];
        m.x = fmaxf(m.x, v.x); m.y = fmaxf(m.y, v.y);
        m.z = fmaxf(m.z, v.z); m.w = fmaxf(m.w, v.w);
    }
    pm[grp][col] = m;
    __syncthreads();

    float4 e;
    if (t < COLS4) {
        float4 a  = pm[0][t];
        float4 c2 = pm[1][t];
        e.x = fmaxf(a.x, c2.x); e.y = fmaxf(a.y, c2.y);
        e.z = fmaxf(a.z, c2.z); e.w = fmaxf(a.w, c2.w);
        float tm = fmaxf(fmaxf(e.x, e.y), fmaxf(e.z, e.w));
        #pragma unroll
        for (int off = 32; off > 0; off >>= 1)
            tm = fmaxf(tm, __shfl_down(tm, off, 64));
        if (lane == 0) sred[wid] = tm;   // wid 0..7
    }
    __syncthreads();
    float M = sred[0];
    #pragma unroll
    for (int i = 1; i < 8; ++i) M = fmaxf(M, sred[i]);

    if (t < COLS4) {
        e.x = __expf(e.x - M); e.y = __expf(e.y - M);
        e.z = __expf(e.z - M); e.w = __expf(e.w - M);
        float ts = (e.x + e.y) + (e.z + e.w);
        #pragma unroll
        for (int off = 32; off > 0; off >>= 1)
            ts += __shfl_down(ts, off, 64);
        if (lane == 0) sred[8 + wid] = ts;
    }
    __syncthreads();

    if (t < COLS4) {
        float S = 0.0f;
        #pragma unroll
        for (int i = 8; i < 16; ++i) S += sred[i];
        const float inv = 1.0f / S;
        float4 gg;
        gg.x = e.x * inv; gg.y = e.y * inv; gg.z = e.z * inv; gg.w = e.w * inv;
        // 4 gate copies: at channels 0, 16, 32, 48 (first channel of each
        // K_B group — read-then-overwritten only by that group's block).
        ob[(size_t)( 0) * COLS4 + t] = gg;
        ob[(size_t)(16) * COLS4 + t] = gg;
        ob[(size_t)(32) * COLS4 + t] = gg;
        ob[(size_t)(48) * COLS4 + t] = gg;
    }
}

// ---------------- K_B: out = gate * x ----------------
// 1024 blocks = 256 rows x 4 channel-groups (16 channels each), 512 threads
// (one float4 column per thread). Each block reads ITS gate copy (channel
// g*16) into registers, syncs, then streams 16 channels; each (block,channel)
// access is a full contiguous 8 KB line.
__global__ __launch_bounds__(512)
void mul_kernel(const float* __restrict__ x, float* __restrict__ out) {
    const int bid = blockIdx.x;
    const int b   = bid >> 2;
    const int g   = bid & 3;
    const int col = threadIdx.x;        // 0..511

    const size_t rbase = (size_t)b * ROW4;
    const float4* __restrict__ x4 = (const float4*)x + rbase;
    float4* o4 = (float4*)out + rbase;

    const int cbase = g * 16;
    const float4 gv = o4[(size_t)cbase * COLS4 + col];   // this block's copy
    __syncthreads();                    // all reads done before any write

    #pragma unroll 4
    for (int c = 0; c < 16; ++c) {
        const size_t idx = (size_t)(cbase + c) * COLS4 + col;
        float4 v = x4[idx];
        float4 o;
        o.x = v.x * gv.x; o.y = v.y * gv.y;
        o.z = v.z * gv.z; o.w = v.w * gv.w;
        o4[idx] = o;
    }
}

extern "C" void kernel_launch(void* const* d_in, const int* in_sizes, int n_in,
                              void* d_out, int out_size, void* d_ws, size_t ws_size,
                              hipStream_t stream) {
    const float* x = (const float*)d_in[0];
    float* out = (float*)d_out;
    gate_kernel<<<B_DIM, 1024, 0, stream>>>(x, out);
    mul_kernel<<<B_DIM * 4, 512, 0, stream>>>(x, out);
}